// Round 1
// baseline (126.292 us; speedup 1.0000x reference)
//
#include <hip/hip_runtime.h>
#include <math.h>

typedef unsigned short ushort_t;
typedef unsigned int uint32_tt;
typedef __attribute__((ext_vector_type(8))) short bf16x8;
typedef __attribute__((ext_vector_type(4))) float f32x4;

#define NR   8
#define NK   10
#define ND   256
#define NDL  10
#define NB   4096
#define NN   100
#define NP   112      // phase-1 padded n (7*16)
#define NP2  128      // padded K over n (4*32)

// ---- workspace layout (bytes) ----
// R9: xb (bf16 x) REMOVED — kernel A reads x f32 directly and packs in-register.
// New: WS_W intermediate w[r][b][n] bf16 (softmax output), 8 MB.
#define WS_GP   0                          // fp32 Gp[8][1000]    (32 KB)
#define WS_U1   32768                      // bf16 U1[8][112][256] = 458752
#define WS_U2   (WS_U1 + 458752)           // bf16 U2[8][256][128] = 524288
#define WS_W    (WS_U2 + 524288)           // bf16 w[8][4096][128] = 8388608
#define WS_NEED (WS_W + 8388608)           // 9,404,416

__device__ __forceinline__ ushort_t f2bf(float f) {
    uint32_tt u = __float_as_uint(f);
    u = (u + 0x7FFF + ((u >> 16) & 1)) >> 16;   // RNE
    return (ushort_t)u;
}

// =====================================================================
// Prep, grid 80 x 256: one block per (r,k). Us[rk] 10KB -> LDS, emit
// Gram (fp32) + U1 slice + U2 slice. (x-conversion branch removed.)
// =====================================================================
__global__ __launch_bounds__(256) void prep_kernel(const float* __restrict__ Us,
                                                   char* __restrict__ ws) {
    __shared__ float lu[ND * NDL];     // 10 KB, layout [D][d] stride 10
    const int tid = threadIdx.x;
    const int rk = blockIdx.x;               // 0..79
    const int r  = rk / NK, k = rk - r * NK;
    const float* U = Us + (size_t)rk * ND * NDL;
    for (int i = tid; i < 640; i += 256)
        ((float4*)lu)[i] = ((const float4*)U)[i];
    __syncthreads();

    // ---- Gram: Gp = 10*I - 5*U^T U (fp32 -> logits stay accurate) ----
    float* Gp = (float*)(ws + WS_GP);
    if (tid < NDL * NDL) {
        int d1 = tid / NDL, d2 = tid - d1 * NDL;
        float acc = 0.f;
        #pragma unroll 8
        for (int Di = 0; Di < ND; ++Di)
            acc += lu[Di * NDL + d1] * lu[Di * NDL + d2];
        Gp[(size_t)rk * 100 + tid] = (d1 == d2 ? 10.0f : 0.0f) - 5.0f * acc;
    }

    // ---- U1[r][k*10+d][D] bf16, coalesced in D ----
    ushort_t* u1 = (ushort_t*)(ws + WS_U1);
    for (int p = tid; p < ND * NDL; p += 256) {
        int d = p >> 8, D = p & 255;
        u1[((size_t)r * NP + k * NDL + d) * ND + D] = f2bf(lu[D * NDL + d]);
    }

    // ---- U2[r][D][k*10..k*10+10) bf16, one D-row per thread ----
    ushort_t* u2 = (ushort_t*)(ws + WS_U2);
    {
        int D = tid;
        uint32_tt* dst = (uint32_tt*)(u2 + ((size_t)r * ND + D) * NP2 + k * NDL);
        const float* src = lu + D * NDL;
        #pragma unroll
        for (int j = 0; j < 5; ++j)
            dst[j] = (uint32_tt)f2bf(src[2 * j]) | ((uint32_tt)f2bf(src[2 * j + 1]) << 16);
    }

    // ---- zero pads (k==9 block only) ----
    if (k == NK - 1) {
        for (int p = tid; p < 12 * ND; p += 256) {
            int n = p >> 8, D = p & 255;
            u1[((size_t)r * NP + 100 + n) * ND + D] = 0;
        }
        uint32_tt* u2u = (uint32_tt*)u2;
        #pragma unroll
        for (int j = 0; j < 14; ++j)
            u2u[((size_t)r * ND + tid) * (NP2 / 2) + 50 + j] = 0;
    }
}

// =====================================================================
// Kernel A: z = U1^T x (MFMA) + softmax -> w[r][b][128] bf16 to ws.
// R9 theory: the fused ksub was latency/occupancy-bound (VGPR>128 -> 2
// blocks/CU, 5-barrier serial chain), not HBM-bound (NT-store null in
// R8). Split at the softmax seam: A is register-lean (~80 VGPR, 16.8 KB
// LDS, 3 barriers) -> 4 blocks/CU, single round of grid 1024.
// x is read f32 directly (prep no longer converts it).
// =====================================================================
__global__ __launch_bounds__(256) void zsoft_kernel(const float* __restrict__ x,
                                                    char* __restrict__ ws) {
    __shared__ __align__(16) char smem[16800];
    float*    zbuf = (float*)smem;               // [32][100] fp32
    ushort_t* wTb  = (ushort_t*)smem;            // [32][136] bf16 (overlay)
    float*    gp   = (float*)(smem + 12800);     // [1000] fp32

    const int tid  = threadIdx.x;
    const int w    = tid >> 6;
    const int lane = tid & 63;
    const int c    = lane & 15;
    const int q    = lane >> 4;
    const int bid  = blockIdx.x;
    const int xcd  = bid & 7;
    const int idx  = bid >> 3;                   // 0..127
    const int r    = idx & 7;
    const int b0   = (xcd * 16 + (idx >> 3)) * 32;
    const int bloc = (w & 1) * 16 + c;           // local b col 0..31
    const int pair = w >> 1;                     // wave pair 0/1

    const float*    xg  = x + (size_t)(b0 + bloc) * ND + q * 8;
    const ushort_t* u1g = (const ushort_t*)(ws + WS_U1) + (size_t)r * NP * ND + c * ND + q * 8;
    const float*    gpg = (const float*)(ws + WS_GP) + (size_t)r * 1000;

    for (int i = tid; i < 1000; i += 256) gp[i] = gpg[i];

    // ---------------- phase 1: direct-global fragments ----------------
    f32x4 acc1[4];
    #pragma unroll
    for (int t = 0; t < 4; ++t) acc1[t] = (f32x4){0.f, 0.f, 0.f, 0.f};

    #pragma unroll
    for (int Dc = 0; Dc < 8; ++Dc) {
        // x fragment: 8 consecutive f32 -> bf16x8 (RNE, identical to old xb path)
        float4 xa = *(const float4*)(xg + Dc * 32);
        float4 xb4 = *(const float4*)(xg + Dc * 32 + 4);
        bf16x8 xf;
        xf[0] = (short)f2bf(xa.x);  xf[1] = (short)f2bf(xa.y);
        xf[2] = (short)f2bf(xa.z);  xf[3] = (short)f2bf(xa.w);
        xf[4] = (short)f2bf(xb4.x); xf[5] = (short)f2bf(xb4.y);
        xf[6] = (short)f2bf(xb4.z); xf[7] = (short)f2bf(xb4.w);

        bf16x8 a[4];
        #pragma unroll
        for (int tt = 0; tt < 4; ++tt) {
            int t = pair * 4 + tt;
            if (t < 7)                            // wave-uniform predicate
                a[tt] = *(const bf16x8*)(u1g + t * 16 * ND + Dc * 32);
        }
        #pragma unroll
        for (int tt = 0; tt < 4; ++tt) {
            int t = pair * 4 + tt;
            if (t < 7)
                acc1[tt] = __builtin_amdgcn_mfma_f32_16x16x32_bf16(a[tt], xf, acc1[tt], 0, 0, 0);
        }
    }

    // ---- dump Z^T C-frags: row n = t*16+q*4+reg, col b = bloc ----
    #pragma unroll
    for (int tt = 0; tt < 4; ++tt) {
        int t = pair * 4 + tt;
        if (t < 7) {
            #pragma unroll
            for (int rg = 0; rg < 4; ++rg) {
                int n = t * 16 + q * 4 + rg;
                if (n < NN) zbuf[bloc * 100 + n] = acc1[tt][rg];
            }
        }
    }
    __syncthreads();

    // ---------------- softmax: b = tid>>3, k split on 8 lanes ----------------
    const int bsm = tid >> 3;
    const int kq  = tid & 7;
    float zk[2][10], ee[2];
    {
        const float* zr = zbuf + bsm * 100;
        float L[2];
        #pragma unroll
        for (int jj = 0; jj < 2; ++jj) {
            int k = kq + 8 * jj;
            L[jj] = -1e30f;
            if (k < NK) {
                #pragma unroll
                for (int d = 0; d < 10; ++d) zk[jj][d] = zr[k * 10 + d];
                const float* g = gp + k * 100;
                float acc = 0.f;
                #pragma unroll
                for (int d1 = 0; d1 < 10; ++d1) {
                    float t2 = 0.f;
                    #pragma unroll
                    for (int d2 = 0; d2 < 10; ++d2) t2 += g[d1 * 10 + d2] * zk[jj][d2];
                    acc += t2 * zk[jj][d1];
                }
                L[jj] = acc;
            }
        }
        float m = fmaxf(L[0], L[1]);
        m = fmaxf(m, __shfl_xor(m, 1));
        m = fmaxf(m, __shfl_xor(m, 2));
        m = fmaxf(m, __shfl_xor(m, 4));
        float s = 0.f;
        #pragma unroll
        for (int jj = 0; jj < 2; ++jj) {
            ee[jj] = (kq + 8 * jj < NK) ? __expf(L[jj] - m) : 0.f;
            s += ee[jj];
        }
        s += __shfl_xor(s, 1);
        s += __shfl_xor(s, 2);
        s += __shfl_xor(s, 4);
        float inv = 1.0f / s;
        #pragma unroll
        for (int jj = 0; jj < 2; ++jj) ee[jj] *= inv;
    }
    __syncthreads();               // all zbuf reads done; wTb overlay safe

    #pragma unroll
    for (int jj = 0; jj < 2; ++jj) {
        int k = kq + 8 * jj;
        if (k < NK) {
            #pragma unroll
            for (int d = 0; d < 10; ++d)
                wTb[bsm * 136 + k * 10 + d] = f2bf(ee[jj] * zk[jj][d]);
        }
    }
    // zero-pad wTb n in [100,128): 14 uints per row, ALL 32 rows
    {
        int row = tid >> 4, p = tid & 15;
        if (row < 32 && p < 14) ((uint32_tt*)wTb)[row * 68 + 50 + p] = 0;
        row = (tid + 256) >> 4;
        if (row < 32 && p < 14) ((uint32_tt*)wTb)[row * 68 + 50 + p] = 0;
    }
    __syncthreads();

    // ---- dump w tile to global ws: 32 rows x 128 bf16 = 2048 u32, coalesced ----
    uint32_tt* wgu = (uint32_tt*)(ws + WS_W + ((size_t)r * NB + b0) * (NP2 * 2));
    const uint32_tt* wTu = (const uint32_tt*)wTb;
    #pragma unroll
    for (int i = tid; i < 2048; i += 256) {
        int row = i >> 6, col = i & 63;
        wgu[row * 64 + col] = wTu[row * 68 + col];
    }
}

// =====================================================================
// Kernel B: out[r][b][D] = U2[r] @ w[r][b]^T. Pure streaming MFMA GEMM:
// ZERO LDS, ZERO barriers. A-frags direct from U2, B-frags direct from
// w, C stored straight to out (C-layout: col=b via c-lane, row=D via
// q*4+reg; 4 q-lanes fill each 64B line -> full-line NT stores, no LDS
// transpose needed). Est ~90 VGPR -> 4 blocks/CU, grid 1024 = 1 round.
// =====================================================================
__global__ __launch_bounds__(256) void outgemm_kernel(const char* __restrict__ ws,
                                                      float* __restrict__ out) {
    const int tid  = threadIdx.x;
    const int w    = tid >> 6;
    const int lane = tid & 63;
    const int c    = lane & 15;
    const int q    = lane >> 4;
    const int bid  = blockIdx.x;
    const int xcd  = bid & 7;
    const int idx  = bid >> 3;
    const int r    = idx & 7;
    const int b0   = (xcd * 16 + (idx >> 3)) * 32;
    const int bloc = (w & 1) * 16 + c;
    const int Dbase = (w >> 1) * 128;

    const ushort_t* u2g = (const ushort_t*)(ws + WS_U2) + (size_t)r * ND * NP2 + c * NP2 + q * 8;
    const ushort_t* wg  = (const ushort_t*)(ws + WS_W)  + ((size_t)r * NB + b0 + bloc) * NP2 + q * 8;

    f32x4 acc[8];
    #pragma unroll
    for (int j = 0; j < 8; ++j) acc[j] = (f32x4){0.f, 0.f, 0.f, 0.f};

    #pragma unroll
    for (int nc = 0; nc < 4; ++nc) {
        bf16x8 bfr = *(const bf16x8*)(wg + nc * 32);
        bf16x8 a[8];
        #pragma unroll
        for (int jj = 0; jj < 8; ++jj)
            a[jj] = *(const bf16x8*)(u2g + (size_t)(Dbase + jj * 16) * NP2 + nc * 32);
        #pragma unroll
        for (int jj = 0; jj < 8; ++jj)
            acc[jj] = __builtin_amdgcn_mfma_f32_16x16x32_bf16(a[jj], bfr, acc[jj], 0, 0, 0);
    }

    const size_t orow = (size_t)r * NB + b0 + bloc;
    #pragma unroll
    for (int jj = 0; jj < 8; ++jj)
        __builtin_nontemporal_store(acc[jj], (f32x4*)(out + orow * ND + Dbase + jj * 16 + q * 4));
}

// =====================================================================
// Fallback (round-2 verified path) if ws is too small for bf16 buffers
// =====================================================================
#define XS_S 68
#define US_S 132
#define ZB_S 104
#define WT_S 68
#define U2_S 68
#define OFF_WT 0
#define OFF_SH 6800
#define OFF_GP 13600
#define SMEM_F 14600

__global__ __launch_bounds__(128) void gram_kernel(const float* __restrict__ Us,
                                                   float* __restrict__ Gp) {
    int rk = blockIdx.x;
    const float* U = Us + (size_t)rk * ND * NDL;
    __shared__ float u[ND * NDL];
    for (int i = threadIdx.x; i < ND * NDL; i += blockDim.x) u[i] = U[i];
    __syncthreads();
    int e = threadIdx.x;
    if (e < NDL * NDL) {
        int d1 = e / NDL, d2 = e % NDL;
        float acc = 0.f;
        #pragma unroll 8
        for (int Di = 0; Di < ND; ++Di)
            acc += u[Di * NDL + d1] * u[Di * NDL + d2];
        Gp[(size_t)rk * (NDL * NDL) + e] = (d1 == d2 ? 10.0f : 0.0f) - 5.0f * acc;
    }
}

__global__ __launch_bounds__(256, 2) void ksub_fused(const float* __restrict__ x,
                                                     const float* __restrict__ Us,
                                                     const float* __restrict__ Gp,
                                                     float* __restrict__ out) {
    __shared__ float smemf[SMEM_F];
    float* wT   = smemf + OFF_WT;
    float* xsf  = smemf + OFF_SH;
    float* usf  = smemf + OFF_SH + 2176;
    float* zbuf = smemf + OFF_SH;
    float* u2   = smemf + OFF_SH;
    float* gp   = smemf + OFF_GP;

    const int tid = threadIdx.x;
    const int r   = blockIdx.y;
    const int b0  = blockIdx.x * 64;

    for (int i = tid; i < NK * NDL * NDL; i += 256)
        gp[i] = Gp[(size_t)r * (NK * NDL * NDL) + i];

    const int nt = tid & 15;
    const int bt = tid >> 4;
    float acc[4][8];
    #pragma unroll
    for (int j = 0; j < 4; ++j)
        #pragma unroll
        for (int i = 0; i < 8; ++i) acc[j][i] = 0.f;

    for (int cch = 0; cch < 8; ++cch) {
        __syncthreads();
        for (int i = tid; i < 512; i += 256) {
            int b = i >> 3, f = i & 7;
            float4 v = ((const float4*)(x + (size_t)(b0 + b) * ND))[cch * 8 + f];
            float* dst = xsf + (f * 4) * XS_S + b;
            dst[0] = v.x; dst[XS_S] = v.y; dst[2 * XS_S] = v.z; dst[3 * XS_S] = v.w;
        }
        for (int p = tid; p < 320; p += 256) {
            int k = p >> 5, Dl = p & 31;
            const float* g = Us + ((size_t)((r * NK + k) * ND) + cch * 32 + Dl) * NDL;
            float* dst = usf + Dl * US_S + k * NDL;
            #pragma unroll
            for (int d = 0; d < 10; ++d) dst[d] = g[d];
        }
        __syncthreads();
        #pragma unroll 4
        for (int Dl = 0; Dl < 32; ++Dl) {
            float4 xv = *(const float4*)(xsf + Dl * XS_S + bt * 4);
            float4 ua = *(const float4*)(usf + Dl * US_S + nt * 8);
            float4 ub = *(const float4*)(usf + Dl * US_S + nt * 8 + 4);
            float xa[4] = {xv.x, xv.y, xv.z, xv.w};
            float uu[8] = {ua.x, ua.y, ua.z, ua.w, ub.x, ub.y, ub.z, ub.w};
            #pragma unroll
            for (int j = 0; j < 4; ++j)
                #pragma unroll
                for (int i = 0; i < 8; ++i) acc[j][i] += xa[j] * uu[i];
        }
    }
    __syncthreads();
    if (nt < 12) {
        #pragma unroll
        for (int j = 0; j < 4; ++j) {
            float* zp = zbuf + (bt * 4 + j) * ZB_S + nt * 8;
            *(float4*)(zp)     = make_float4(acc[j][0], acc[j][1], acc[j][2], acc[j][3]);
            *(float4*)(zp + 4) = make_float4(acc[j][4], acc[j][5], acc[j][6], acc[j][7]);
        }
    } else if (nt == 12) {
        #pragma unroll
        for (int j = 0; j < 4; ++j) {
            float* zp = zbuf + (bt * 4 + j) * ZB_S + 96;
            *(float4*)(zp) = make_float4(acc[j][0], acc[j][1], acc[j][2], acc[j][3]);
        }
    }
    __syncthreads();
    if (tid < 64) {
        const int b_l = tid;
        const float* zrow = zbuf + b_l * ZB_S;
        float L[10];
        #pragma unroll
        for (int k = 0; k < NK; ++k) {
            float zkk[10];
            #pragma unroll
            for (int d = 0; d < 10; ++d) zkk[d] = zrow[k * 10 + d];
            const float* g = gp + k * 100;
            float a2 = 0.f;
            #pragma unroll
            for (int d1 = 0; d1 < 10; ++d1) {
                float t = 0.f;
                #pragma unroll
                for (int d2 = 0; d2 < 10; ++d2) t += g[d1 * 10 + d2] * zkk[d2];
                a2 += t * zkk[d1];
            }
            L[k] = a2;
        }
        float m = L[0];
        #pragma unroll
        for (int k = 1; k < NK; ++k) m = fmaxf(m, L[k]);
        float e[10], s = 0.f;
        #pragma unroll
        for (int k = 0; k < NK; ++k) { e[k] = __expf(L[k] - m); s += e[k]; }
        float inv = 1.0f / s;
        #pragma unroll
        for (int k = 0; k < NK; ++k) {
            float ck = e[k] * inv;
            #pragma unroll
            for (int d = 0; d < 10; ++d)
                wT[(k * 10 + d) * WT_S + b_l] = ck * zrow[k * 10 + d];
        }
    }
    const int Dt  = tid & 15;
    const int bt2 = tid >> 4;
    for (int c2 = 0; c2 < 4; ++c2) {
        __syncthreads();
        for (int p = tid; p < 640; p += 256) {
            int k = p >> 6, Dl = p & 63;
            const float* g = Us + ((size_t)((r * NK + k) * ND) + c2 * 64 + Dl) * NDL;
            float* dst = u2 + (k * NDL) * U2_S + Dl;
            #pragma unroll
            for (int d = 0; d < 10; ++d) dst[d * U2_S] = g[d];
        }
        __syncthreads();
        float o[4][4];
        #pragma unroll
        for (int j = 0; j < 4; ++j)
            #pragma unroll
            for (int i = 0; i < 4; ++i) o[j][i] = 0.f;
        #pragma unroll 4
        for (int n = 0; n < NN; ++n) {
            float4 wv = *(const float4*)(wT + n * WT_S + bt2 * 4);
            float4 uv = *(const float4*)(u2 + n * U2_S + Dt * 4);
            float wa[4] = {wv.x, wv.y, wv.z, wv.w};
            float ub[4] = {uv.x, uv.y, uv.z, uv.w};
            #pragma unroll
            for (int j = 0; j < 4; ++j)
                #pragma unroll
                for (int i = 0; i < 4; ++i) o[j][i] += wa[j] * ub[i];
        }
        #pragma unroll
        for (int j = 0; j < 4; ++j) {
            float* op = out + ((size_t)r * NB + b0 + bt2 * 4 + j) * ND + c2 * 64 + Dt * 4;
            *(float4*)op = make_float4(o[j][0], o[j][1], o[j][2], o[j][3]);
        }
    }
}

extern "C" void kernel_launch(void* const* d_in, const int* in_sizes, int n_in,
                              void* d_out, int out_size, void* d_ws, size_t ws_size,
                              hipStream_t stream) {
    const float* x  = (const float*)d_in[0];
    const float* Us = (const float*)d_in[1];
    float* out = (float*)d_out;

    if (ws_size >= (size_t)WS_NEED) {
        prep_kernel<<<dim3(80), 256, 0, stream>>>(Us, (char*)d_ws);
        zsoft_kernel<<<dim3(1024), 256, 0, stream>>>(x, (char*)d_ws);
        outgemm_kernel<<<dim3(1024), 256, 0, stream>>>((const char*)d_ws, out);
    } else {
        gram_kernel<<<dim3(NR * NK), 128, 0, stream>>>(Us, (float*)d_ws);
        ksub_fused<<<dim3(NB / 64, NR), 256, 0, stream>>>(x, Us, (float*)d_ws, out);
    }
}